// Round 4
// baseline (221.932 us; speedup 1.0000x reference)
//
#include <hip/hip_runtime.h>
#include <math.h>

// Problem constants (fixed by the reference setup_inputs): B=2, P=8192, K=16
#define PP    8192
#define NB    2
#define NPTS  16384          // NB * PP
#define KNN   16
#define EPSV  1e-17f

#define NCELL 4096           // 16^3 Morton cells per batch
#define NTILE 128            // tiles of 64 sorted points per batch
#define KEY_BIG 3.0e38f      // > any real key, finite

// ---- workspace layout (floats) ----------------------------------------------
// [idx 262144][dist 262144][phi 262144]
// [region @786432: spts4 (65536) @786432 | sid (16384) @851968 | aabb (2048) @868352
//                  -- dead after knn; nw (262144) written here by denoise2]
// [n1 @1048576][n2 @1097728][part @1146880 (64)]

__device__ __forceinline__ int cell_of(float x, float y, float z) {
    int cx = (int)floorf((x + 4.0f) * 2.0f); cx = min(15, max(0, cx));
    int cy = (int)floorf((y + 4.0f) * 2.0f); cy = min(15, max(0, cy));
    int cz = (int)floorf((z + 4.0f) * 2.0f); cz = min(15, max(0, cz));
    #define MORT4(v) (((v)&1) | (((v)&2)<<2) | (((v)&4)<<4) | (((v)&8)<<6))
    return MORT4(cx) | (MORT4(cy) << 1) | (MORT4(cz) << 2);
    #undef MORT4
}

// ---- K0: fused counting sort + tile AABBs, one block per batch --------------
__global__ __launch_bounds__(1024) void sort_kernel(const float* __restrict__ pts,
                                                    float4* __restrict__ spts4,
                                                    int* __restrict__ sid,
                                                    float4* __restrict__ aabb) {
    __shared__ int h[NCELL];         // 16 KB: histogram, then cursors
    __shared__ int sbuf[1024];       // 4 KB: scan buffer
    const int t = threadIdx.x;
    const int batch = blockIdx.x;
    const float* bp = pts + (size_t)batch * PP * 3;

    for (int k = t; k < NCELL; k += 1024) h[k] = 0;
    __syncthreads();

    float px[8], py[8], pz[8]; int pc[8];
#pragma unroll
    for (int k = 0; k < 8; ++k) {
        const int p = k * 1024 + t;                  // coalesced
        const float x = bp[p * 3 + 0];
        const float y = bp[p * 3 + 1];
        const float z = bp[p * 3 + 2];
        px[k] = x; py[k] = y; pz[k] = z;
        const int c = cell_of(x, y, z);
        pc[k] = c;
        atomicAdd(&h[c], 1);
    }
    __syncthreads();

    // exclusive scan over 4096 cells (4 per thread + Hillis-Steele over 1024)
    int loc[4]; int s = 0;
#pragma unroll
    for (int k = 0; k < 4; ++k) { loc[k] = s; s += h[t * 4 + k]; }
    sbuf[t] = s; __syncthreads();
    for (int off = 1; off < 1024; off <<= 1) {
        int v = (t >= off) ? sbuf[t - off] : 0;
        __syncthreads();
        sbuf[t] += v;
        __syncthreads();
    }
    const int excl = sbuf[t] - s;
#pragma unroll
    for (int k = 0; k < 4; ++k) h[t * 4 + k] = excl + loc[k];   // cursors
    __syncthreads();

    const int sbase = batch * PP;
#pragma unroll
    for (int k = 0; k < 8; ++k) {
        const int pos = atomicAdd(&h[pc[k]], 1);
        const int p = k * 1024 + t;
        spts4[sbase + pos] = make_float4(px[k], py[k], pz[k],
                                         px[k] * px[k] + py[k] * py[k] + pz[k] * pz[k]);
        sid[sbase + pos] = p;
    }
    __syncthreads();                                 // stores drained (vmcnt 0)

    if (t < NTILE) {                                 // per-tile AABB
        float4 c0 = spts4[sbase + t * 64];
        float lx = c0.x, ly = c0.y, lz = c0.z, hx = c0.x, hy = c0.y, hz = c0.z;
        for (int e = 1; e < 64; ++e) {
            float4 c = spts4[sbase + t * 64 + e];
            lx = fminf(lx, c.x); ly = fminf(ly, c.y); lz = fminf(lz, c.z);
            hx = fmaxf(hx, c.x); hy = fmaxf(hy, c.y); hz = fmaxf(hz, c.z);
        }
        aabb[(batch * NTILE + t) * 2 + 0] = make_float4(lx, ly, lz, 0.f);
        aabb[(batch * NTILE + t) * 2 + 1] = make_float4(hx, hy, hz, 0.f);
    }
}

// ---- K1: grid-pruned exact 16-NN + fused denoise1 ---------------------------
// Block: 8 waves, 64 queries (sorted tile t_q). Seed: wave w scans full tile
// (t_q+w)&127 from LDS. tau[lane] = min over waves of keys[15] (valid upper
// bound on final 16th key). Block-uniform hit list via box-box dist < taumax,
// then double-buffered LDS staging; per-wave adaptive ballot skip.
#define TPB 512
__global__ __launch_bounds__(TPB) void knn_kernel(const float* __restrict__ pts,
                                                  const float* __restrict__ normals,
                                                  const float4* __restrict__ spts4,
                                                  const int* __restrict__ sid,
                                                  const float4* __restrict__ aabb,
                                                  int* __restrict__ out_idx,
                                                  float* __restrict__ out_dist,
                                                  float* __restrict__ phi_out,
                                                  float* __restrict__ n1_out) {
    __shared__ float4 lds_aabb[2 * NTILE];           // 4 KB
    __shared__ float4 seedF[8 * 64];                 // 8 KB
    __shared__ int    seedI[8 * 64];                 // 2 KB
    __shared__ float4 bufF[2][64];                   // 2 KB
    __shared__ int    bufI[2][64];                   // 0.5 KB
    __shared__ unsigned int tau_u[64];
    __shared__ int    list_sh[120];
    __shared__ int    cnt_sh[2];
    __shared__ float  taumax_sh;
    __shared__ float  smerge[8 * KNN * 64];          // 32 KB

    const int tid   = threadIdx.x;
    const int lane  = tid & 63;
    const int wave  = tid >> 6;
    const int batch = blockIdx.x >> 7;
    const int t_q   = blockIdx.x & (NTILE - 1);
    const int sbase = batch * PP;

    if (tid < 2 * NTILE) lds_aabb[tid] = aabb[batch * 2 * NTILE + tid];
    if (tid < 64) tau_u[tid] = 0xFFFFFFFFu;
    {   // stage the 8 seed tiles (t_q .. t_q+7 mod 128); wave w stages tile w
        const int g = (t_q + wave) & (NTILE - 1);
        seedF[wave * 64 + lane] = spts4[sbase + g * 64 + lane];
        seedI[wave * 64 + lane] = sid[sbase + g * 64 + lane];
    }
    __syncthreads();

    // query = lane's point of own tile (seed slot 0)
    const float4 q4  = seedF[lane];
    const int    qid = seedI[lane];                  // original id 0..8191
    const float qx = q4.x, qy = q4.y, qz = q4.z, d2q = q4.w;

    float keys[KNN];
#pragma unroll
    for (int s = 0; s < KNN; ++s) keys[s] = KEY_BIG;

    // ---- seed: wave w scans its full staged tile (64 candidates) ----
    {
        const float4* myF = &seedF[wave * 64];
        const int*    myI = &seedI[wave * 64];
#pragma unroll 8
        for (int jj = 0; jj < 64; ++jj) {
            const float4 c4 = myF[jj];               // LDS broadcast
            const int sj = myI[jj];
            const float dot = __builtin_fmaf(qz, c4.z,
                              __builtin_fmaf(qy, c4.y, qx * c4.x));
            const float d = __builtin_fmaf(-2.0f, dot, d2q + c4.w);
            const float dc = fmaxf(d, 0.0f);
            unsigned int kb = (__float_as_uint(dc) & 0xFFFFE000u) | (unsigned int)sj;
            float key = __uint_as_float(kb);
            if (sj == qid) key = KEY_BIG;            // exclude self
#pragma unroll
            for (int s = KNN - 1; s >= 1; --s)
                keys[s] = __builtin_amdgcn_fmed3f(keys[s - 1], key, keys[s]);
            keys[0] = fminf(keys[0], key);
        }
    }

    // ---- tau reduce (per-lane min over waves; non-negative => uint order ok)
    atomicMin(&tau_u[lane], __float_as_uint(keys[KNN - 1]));
    __syncthreads();
    if (wave == 0) {
        float tv = __uint_as_float(tau_u[lane]);
#pragma unroll
        for (int m = 1; m < 64; m <<= 1) tv = fmaxf(tv, __shfl_xor(tv, m, 64));
        if (lane == 0) taumax_sh = tv;
    }
    __syncthreads();

    // ---- block-uniform hit list: box-box dist(tile, query tile) < taumax ----
    const float4 qlo = lds_aabb[2 * t_q + 0];
    const float4 qhi = lds_aabb[2 * t_q + 1];
    bool pred = false; int t_abs = 0, rank = 0;
    if (wave < 2) {
        if (tid < 120) {
            t_abs = (t_q + 8 + tid) & (NTILE - 1);
            const float4 lo = lds_aabb[2 * t_abs + 0];
            const float4 hi = lds_aabb[2 * t_abs + 1];
            const float gx = fmaxf(fmaxf(lo.x - qhi.x, qlo.x - hi.x), 0.0f);
            const float gy = fmaxf(fmaxf(lo.y - qhi.y, qlo.y - hi.y), 0.0f);
            const float gz = fmaxf(fmaxf(lo.z - qhi.z, qlo.z - hi.z), 0.0f);
            const float bb = gx * gx + gy * gy + gz * gz;
            const float bbk = __uint_as_float(__float_as_uint(bb) & 0xFFFFE000u);
            pred = bbk < taumax_sh;
        }
        const unsigned long long bal = __ballot(pred);
        rank = __popcll(bal & ((1ull << lane) - 1ull));
        if (lane == 0) cnt_sh[wave] = __popcll(bal);
    }
    __syncthreads();
    if (wave < 2 && pred) {
        const int off = (wave == 1) ? cnt_sh[0] : 0;
        list_sh[off + rank] = t_abs;
    }
    __syncthreads();
    const int nlist = cnt_sh[0] + cnt_sh[1];

    // ---- stage-B: double-buffered scan of listed tiles ----
    if (nlist > 0 && tid < 128) {
        const int t0 = list_sh[0];
        if (tid < 64) bufF[0][tid] = spts4[sbase + t0 * 64 + tid];
        else          bufI[0][tid - 64] = sid[sbase + t0 * 64 + (tid - 64)];
    }
    __syncthreads();
    for (int li = 0; li < nlist; ++li) {
        const int cur = li & 1;
        float4 pf; int sf;
        const bool havenext = (li + 1 < nlist);
        if (havenext && tid < 128) {                 // issue next-tile loads
            const int tn = list_sh[li + 1];
            if (tid < 64) pf = spts4[sbase + tn * 64 + tid];
            else          sf = sid[sbase + tn * 64 + (tid - 64)];
        }
        {   // process current tile from LDS, per-wave adaptive skip
            const int ta = list_sh[li];
            const float4 lo = lds_aabb[2 * ta + 0];
            const float4 hi = lds_aabb[2 * ta + 1];
            const float ax = fmaxf(fmaxf(lo.x - qx, qx - hi.x), 0.0f);
            const float ay = fmaxf(fmaxf(lo.y - qy, qy - hi.y), 0.0f);
            const float az = fmaxf(fmaxf(lo.z - qz, qz - hi.z), 0.0f);
            const float bd = ax * ax + ay * ay + az * az;
            const float bdk = __uint_as_float(__float_as_uint(bd) & 0xFFFFE000u);
            if (__ballot(bdk < keys[KNN - 1]) != 0ull) {
#pragma unroll
                for (int k = 0; k < 8; ++k) {
                    const int jj = wave + 8 * k;
                    const float4 c4 = bufF[cur][jj];
                    const int sj = bufI[cur][jj];
                    const float dot = __builtin_fmaf(qz, c4.z,
                                      __builtin_fmaf(qy, c4.y, qx * c4.x));
                    const float d = __builtin_fmaf(-2.0f, dot, d2q + c4.w);
                    const float dc = fmaxf(d, 0.0f);
                    unsigned int kb = (__float_as_uint(dc) & 0xFFFFE000u) | (unsigned int)sj;
                    float key = __uint_as_float(kb);
                    if (sj == qid) key = KEY_BIG;
#pragma unroll
                    for (int s = KNN - 1; s >= 1; --s)
                        keys[s] = __builtin_amdgcn_fmed3f(keys[s - 1], key, keys[s]);
                    keys[0] = fminf(keys[0], key);
                }
            }
        }
        if (havenext && tid < 128) {                 // commit next tile to LDS
            if (tid < 64) bufF[cur ^ 1][tid] = pf;
            else          bufI[cur ^ 1][tid - 64] = sf;
        }
        __syncthreads();
    }

    // ---- merge 8 per-wave top-16s, then fused epilogue (wave 0) ----
    __syncthreads();
#pragma unroll
    for (int s = 0; s < KNN; ++s) smerge[(wave * KNN + s) * 64 + lane] = keys[s];
    __syncthreads();

    if (wave == 0) {
        for (int w = 1; w < 8; ++w) {
#pragma unroll
            for (int s2 = 0; s2 < KNN; ++s2) {
                const float key = smerge[(w * KNN + s2) * 64 + lane];
#pragma unroll
                for (int s = KNN - 1; s >= 1; --s)
                    keys[s] = __builtin_amdgcn_fmed3f(keys[s - 1], key, keys[s]);
                keys[0] = fminf(keys[0], key);
            }
        }
        // epilogue: exact dists, idx, phi, n1 (fused denoise1). orig-id rows.
        const float* bp = pts + (size_t)batch * PP * 3;
        const float* bn = normals + (size_t)batch * PP * 3;
        const int qrow = batch * PP + qid;
        float d[KNN]; int jidx[KNN];
#pragma unroll
        for (int s = 0; s < KNN; ++s) {
            const int j = (int)(__float_as_uint(keys[s]) & 0x1FFFu);
            jidx[s] = j;
            out_idx[qrow * KNN + s] = j;
            const float x = bp[j * 3 + 0];
            const float y = bp[j * 3 + 1];
            const float z = bp[j * 3 + 2];
            const float dot = qx * x + qy * y + qz * z;
            const float dd = (d2q + (x * x + y * y + z * z)) - (dot + dot);
            const float dcl = fmaxf(dd, 0.0f);
            out_dist[qrow * KNN + s] = dcl;
            d[s] = dcl;
        }
        float d1 = d[0];
#pragma unroll
        for (int s = 1; s < KNN; ++s) d1 = fminf(d1, d[s]);
        float s0 = d1 * 8.0f;                        // 2 * FILTER_SCALE^2
        const float sden = (s0 < EPSV) ? EPSV : s0;
        float sphi = 0.f, nx = 0.f, ny = 0.f, nz = 0.f;
#pragma unroll
        for (int s = 0; s < KNN; ++s) {
            float w = fmaxf(1.0f - d[s] / sden, 0.0f);
            float w2 = w * w;
            float ph = w2 * w2;
            phi_out[qrow * KNN + s] = ph;
            const int j = jidx[s];
            nx += ph * bn[j * 3 + 0];
            ny += ph * bn[j * 3 + 1];
            nz += ph * bn[j * 3 + 2];
            sphi += ph;
        }
        const float den = (sphi < EPSV) ? EPSV : sphi;
        n1_out[qrow * 3 + 0] = nx / den;
        n1_out[qrow * 3 + 1] = ny / den;
        n1_out[qrow * 3 + 2] = nz / den;
    }
}

// ---- K3: normal_w + second denoise (n2) -------------------------------------
__global__ void denoise2_kernel(const int* __restrict__ idx,
                                const float* __restrict__ phi,
                                const float* __restrict__ n1,
                                float* __restrict__ nw_out,
                                float* __restrict__ n2_out) {
    const int q = blockIdx.x * blockDim.x + threadIdx.x;
    if (q >= NPTS) return;
    const int b = q >> 13;
    const int gbase = b * PP;
    const float INV_SIG = 1.0f / (0.75f * 0.75f);

    const float ax = n1[q * 3 + 0];
    const float ay = n1[q * 3 + 1];
    const float az = n1[q * 3 + 2];
    const float an = fmaxf(sqrtf(ax * ax + ay * ay + az * az), 1e-12f);
    const float rx = ax / an, ry = ay / an, rz = az / an;

    float swn = 0.f, ox = 0.f, oy = 0.f, oz = 0.f;
#pragma unroll
    for (int s = 0; s < KNN; ++s) {
        const int j = idx[q * KNN + s];
        const float bx = n1[(gbase + j) * 3 + 0];
        const float by = n1[(gbase + j) * 3 + 1];
        const float bz = n1[(gbase + j) * 3 + 2];
        const float bnn = fmaxf(sqrtf(bx * bx + by * by + bz * bz), 1e-12f);
        const float ux = bx / bnn - rx;
        const float uy = by / bnn - ry;
        const float uz = bz / bnn - rz;
        const float dd = ux * ux + uy * uy + uz * uz;
        const float nw = expf(-dd * INV_SIG);
        nw_out[q * KNN + s] = nw;
        const float wk = phi[q * KNN + s] * nw;
        ox += wk * bx;
        oy += wk * by;
        oz += wk * bz;
        swn += wk;
    }
    const float den = (swn < EPSV) ? EPSV : swn;
    n2_out[q * 3 + 0] = ox / den;
    n2_out[q * 3 + 1] = oy / den;
    n2_out[q * 3 + 2] = oz / den;
}

// ---- K4: weights_proj + point-to-plane loss, per-block partial sums ---------
__global__ __launch_bounds__(256) void loss_kernel(const float* __restrict__ pts,
                            const int* __restrict__ idx,
                            const float* __restrict__ dist,
                            const float* __restrict__ phi,
                            const float* __restrict__ nw,
                            const float* __restrict__ n2,
                            float* __restrict__ partial) {
    __shared__ float red[4];
    const int q = blockIdx.x * 256 + threadIdx.x;
    const int b = q >> 13;
    const int il = q & (PP - 1);
    const float* bp = pts + (size_t)b * PP * 3;
    const int gbase = b * PP;

    const float px = bp[il * 3 + 0];
    const float py = bp[il * 3 + 1];
    const float pz = bp[il * 3 + 2];

    float d[KNN];
#pragma unroll
    for (int s = 0; s < KNN; ++s) d[s] = dist[q * KNN + s];
    float d1 = d[0];
#pragma unroll
    for (int s = 1; s < KNN; ++s) d1 = fminf(d1, d[s]);
    const float thresh = 4.0f * d1;

    float num = 0.f, den = 0.f;
#pragma unroll
    for (int s = 0; s < KNN; ++s) {
        float w = phi[q * KNN + s] * nw[q * KNN + s];
        if (d[s] > thresh) w = 0.f;
        const int j = idx[q * KNN + s];
        const float nx = n2[(gbase + j) * 3 + 0];
        const float ny = n2[(gbase + j) * 3 + 1];
        const float nz = n2[(gbase + j) * 3 + 2];
        const float dts = (bp[j * 3 + 0] - px) * nx +
                          (bp[j * 3 + 1] - py) * ny +
                          (bp[j * 3 + 2] - pz) * nz;
        num += dts * dts * w;
        den += w;
    }
    const float dd = (den < EPSV) ? EPSV : den;
    float loss = num / dd;

#pragma unroll
    for (int off = 32; off >= 1; off >>= 1) loss += __shfl_down(loss, off, 64);
    if ((threadIdx.x & 63) == 0) red[threadIdx.x >> 6] = loss;
    __syncthreads();
    if (threadIdx.x == 0) partial[blockIdx.x] = red[0] + red[1] + red[2] + red[3];
}

// ---- K5: final mean ---------------------------------------------------------
__global__ void finalize_kernel(const float* __restrict__ partial,
                                float* __restrict__ out) {
    float v = partial[threadIdx.x];                  // 64 partials
#pragma unroll
    for (int off = 32; off >= 1; off >>= 1) v += __shfl_down(v, off, 64);
    if (threadIdx.x == 0) out[0] = v / (float)NPTS;
}

// ---- launch -----------------------------------------------------------------
extern "C" void kernel_launch(void* const* d_in, const int* in_sizes, int n_in,
                              void* d_out, int out_size, void* d_ws, size_t ws_size,
                              hipStream_t stream) {
    const float* points  = (const float*)d_in[0];
    const float* normals = (const float*)d_in[1];
    float* out = (float*)d_out;

    float* wsf     = (float*)d_ws;
    int*   w_idx   = (int*)wsf;                      // @0       262144 ints
    float* w_dist  = wsf + 262144;
    float* w_phi   = wsf + 524288;
    float* w_nw    = wsf + 786432;                   // overlaps sort scratch
    float4* w_spts = (float4*)(wsf + 786432);        // 16384 float4
    int*   w_sid   = (int*)(wsf + 851968);           // 16384 ints
    float4* w_aabb = (float4*)(wsf + 868352);        // 512 float4
    float* w_n1    = wsf + 1048576;
    float* w_n2    = wsf + 1097728;
    float* w_part  = wsf + 1146880;                  // 64

    sort_kernel<<<2, 1024, 0, stream>>>(points, w_spts, w_sid, w_aabb);
    knn_kernel<<<256, TPB, 0, stream>>>(points, normals, w_spts, w_sid, w_aabb,
                                        w_idx, w_dist, w_phi, w_n1);
    denoise2_kernel<<<NPTS / 256, 256, 0, stream>>>(w_idx, w_phi, w_n1, w_nw, w_n2);
    loss_kernel<<<NPTS / 256, 256, 0, stream>>>(points, w_idx, w_dist, w_phi, w_nw, w_n2, w_part);
    finalize_kernel<<<1, 64, 0, stream>>>(w_part, out);
}